// Round 2
// baseline (218.842 us; speedup 1.0000x reference)
//
#include <hip/hip_runtime.h>

// Problem constants
#define S_LEN 2048
#define NH    16
#define DH    64
#define DM    1024
#define NQKV  3072

typedef __attribute__((ext_vector_type(8))) __bf16 bf16x8;
typedef __attribute__((ext_vector_type(4))) float  f32x4;
typedef unsigned short ushort_t;

static __device__ __forceinline__ unsigned short bf16b(float f) {
  return __builtin_bit_cast(unsigned short, (__bf16)f);
}

static __device__ __forceinline__ float exp2v(float x) {
  return __builtin_amdgcn_exp2f(x);   // v_exp_f32: D = 2^S0
}

static __device__ __forceinline__ bf16x8 pack8(float4 f0, float4 f1) {
  uint4 v;
  v.x = ((unsigned)bf16b(f0.y) << 16) | bf16b(f0.x);
  v.y = ((unsigned)bf16b(f0.w) << 16) | bf16b(f0.z);
  v.z = ((unsigned)bf16b(f1.y) << 16) | bf16b(f1.x);
  v.w = ((unsigned)bf16b(f1.w) << 16) | bf16b(f1.z);
  return __builtin_bit_cast(bf16x8, v);
}

static __device__ __forceinline__ void glds16(const void* g, void* l) {
  __builtin_amdgcn_global_load_lds((const __attribute__((address_space(1))) unsigned int*)g,
                                   (__attribute__((address_space(3))) unsigned int*)l, 16, 0, 0);
}

// ---------------- workspace layout (bytes) ----------------
#define OFF_WT  65536ull                          // 3072*1024*2
#define OFF_WOT 6356992ull                        // 1024*1024*2
#define OFF_Q   8454144ull                        // 8 MB
#define OFF_K   16842752ull                       // 8 MB
#define OFF_V   25231360ull                       // 8 MB
#define OFF_AO  33619968ull                       // 8 MB (xb before attn, AO after)

// ---------------- fused prep: fold (MFMA) | transpose | castx ----------------
// blocks 0..255: fold Wq/Wk via F @ W^T; 256..767: transpose v-part + wout; 768..2815: cast x.
__global__ __launch_bounds__(256) void k_prep(const float* __restrict__ wqkv,
                                              const float* __restrict__ wout,
                                              const float* __restrict__ x,
                                              const float* __restrict__ logits,
                                              unsigned short* __restrict__ Wt,
                                              unsigned short* __restrict__ Wot,
                                              unsigned short* __restrict__ xb) {
  __shared__ __align__(16) char sbuf[16640];
  int bid = blockIdx.x;
  int t = threadIdx.x;

  if (bid < 256) {
    // ---- fold: Wt[base+j][k] = sum_i F[j][i] * W[k][base+i], via MFMA ----
    float* msk = (float*)sbuf;                    // 33 f
    float* Kd  = (float*)(sbuf + 144);            // 64 f
    ushort_t (*Fb)[72] = (ushort_t(*)[72])(sbuf + 416);  // 64x72 bf16
    if (t < 33) msk[t] = 1.0f / (1.0f + __expf(-logits[t]));
    __syncthreads();
    if (t < 64) {
      float acc = msk[0];
      #pragma unroll
      for (int f = 1; f < 32; ++f) {
        int r = (f * t) & 63;
        acc += 2.0f * msk[f] * __cosf((float)r * (6.28318530717958647692f / 64.0f));
      }
      acc += msk[32] * ((t & 1) ? -1.0f : 1.0f);
      Kd[t] = acc * (1.0f / 64.0f);
    }
    __syncthreads();
    for (int idx = t; idx < 4096; idx += 256) {
      int j = idx >> 6, i = idx & 63;
      Fb[j][i] = bf16b(Kd[(j - i) & 63]);
    }
    __syncthreads();

    int lane = t & 63, w = t >> 6;
    int m16 = lane & 15, quad = lane >> 4;
    int kx = bid >> 5, yy = bid & 31;
    int which = yy >> 4, h = yy & 15;
    int base = which * 1024 + h * 64;

    bf16x8 af0 = *(const bf16x8*)(&Fb[w * 16 + m16][quad * 8]);
    bf16x8 af1 = *(const bf16x8*)(&Fb[w * 16 + m16][32 + quad * 8]);

    f32x4 acc[8] = {};
    #pragma unroll 2
    for (int n = 0; n < 8; ++n) {
      const float* Wg = wqkv + (size_t)(kx * 128 + n * 16 + m16) * NQKV + base + quad * 8;
      float4 a0 = *(const float4*)(Wg);
      float4 a1 = *(const float4*)(Wg + 4);
      float4 b0 = *(const float4*)(Wg + 32);
      float4 b1 = *(const float4*)(Wg + 36);
      acc[n] = __builtin_amdgcn_mfma_f32_16x16x32_bf16(af0, pack8(a0, a1), acc[n], 0, 0, 0);
      acc[n] = __builtin_amdgcn_mfma_f32_16x16x32_bf16(af1, pack8(b0, b1), acc[n], 0, 0, 0);
    }
    float sc = (which == 0) ? 0.18033688011112042f : 1.0f;   // 0.125 * log2(e) into q
    #pragma unroll
    for (int n = 0; n < 8; ++n) {
      #pragma unroll
      for (int r = 0; r < 4; ++r) {
        int j = w * 16 + quad * 4 + r;
        Wt[(size_t)(base + j) * DM + kx * 128 + n * 16 + m16] = bf16b(acc[n][r] * sc);
      }
    }
  } else if (bid < 768) {
    // ---- transpose+cast: v-part of w_qkv and w_out ----
    float (*Ts)[65] = (float(*)[65])sbuf;
    int b1 = bid - 256;
    if (b1 < 256) {
      int kt = b1 & 15, nt = b1 >> 4;
      int cb = 2048 + nt * 64, kbase = kt * 64;
      #pragma unroll
      for (int p = 0; p < 16; ++p) {
        int kk = p * 4 + (t >> 6);
        Ts[kk][t & 63] = wqkv[(size_t)(kbase + kk) * NQKV + cb + (t & 63)];
      }
      __syncthreads();
      #pragma unroll
      for (int p = 0; p < 16; ++p) {
        int nn = p * 4 + (t >> 6);
        Wt[(size_t)(cb + nn) * DM + kbase + (t & 63)] = bf16b(Ts[t & 63][nn]);
      }
    } else {
      int b2 = b1 - 256;
      int kt = b2 & 15, nt = b2 >> 4;
      int cb = nt * 64, kbase = kt * 64;
      #pragma unroll
      for (int p = 0; p < 16; ++p) {
        int kk = p * 4 + (t >> 6);
        Ts[kk][t & 63] = wout[(size_t)(kbase + kk) * DM + cb + (t & 63)];
      }
      __syncthreads();
      #pragma unroll
      for (int p = 0; p < 16; ++p) {
        int nn = p * 4 + (t >> 6);
        Wot[(size_t)(cb + nn) * DM + kbase + (t & 63)] = bf16b(Ts[t & 63][nn]);
      }
    }
  } else {
    // ---- x -> bf16 ----
    size_t i = ((size_t)(bid - 768) * 256 + t) * 8;
    const float4* xp = (const float4*)(x + i);
    float4 a = xp[0], b = xp[1];
    uint4 v;
    v.x = ((unsigned)bf16b(a.y) << 16) | bf16b(a.x);
    v.y = ((unsigned)bf16b(a.w) << 16) | bf16b(a.z);
    v.z = ((unsigned)bf16b(b.y) << 16) | bf16b(b.x);
    v.w = ((unsigned)bf16b(b.w) << 16) | bf16b(b.z);
    *(uint4*)(xb + i) = v;
  }
}

// ---------------- 128x128-tile GEMM core, m97-style: global_load_lds + XOR swizzle ----------------
__device__ __forceinline__ void gemm_core_async(const unsigned short* __restrict__ A,
                                                const unsigned short* __restrict__ Bw,
                                                int bm, int bn, unsigned short* smem,
                                                f32x4 (&acc)[4][4]) {
  unsigned short* As = smem;           // 8192 shorts
  unsigned short* Bs = smem + 8192;
  int t = threadIdx.x, lane = t & 63, w = t >> 6;
  int m16 = lane & 15, quad = lane >> 4;
  int wr = (w >> 1) * 64, wc = (w & 1) * 64;
  int lr = lane >> 3, lc = lane & 7;
  int gc = lc ^ lr;
  int xr = m16 & 7;
  const unsigned short* Agb = A  + (size_t)(bm * 128) * DM + gc * 8;
  const unsigned short* Bgb = Bw + (size_t)(bn * 128) * DM + gc * 8;

  for (int k0 = 0; k0 < DM; k0 += 64) {
    #pragma unroll
    for (int p = 0; p < 4; ++p) {
      int row = p * 32 + w * 8 + lr;
      glds16(Agb + (size_t)row * DM + k0, As + row * 64 + lc * 8);
      glds16(Bgb + (size_t)row * DM + k0, Bs + row * 64 + lc * 8);
    }
    __syncthreads();
    #pragma unroll
    for (int kk = 0; kk < 2; ++kk) {
      bf16x8 af[4], bfr[4];
      #pragma unroll
      for (int i = 0; i < 4; ++i)
        af[i] = *(const bf16x8*)(As + (wr + i * 16 + m16) * 64 + ((kk * 4 + quad) ^ xr) * 8);
      #pragma unroll
      for (int j = 0; j < 4; ++j)
        bfr[j] = *(const bf16x8*)(Bs + (wc + j * 16 + m16) * 64 + ((kk * 4 + quad) ^ xr) * 8);
      #pragma unroll
      for (int i = 0; i < 4; ++i)
        #pragma unroll
        for (int j = 0; j < 4; ++j)
          acc[i][j] = __builtin_amdgcn_mfma_f32_16x16x32_bf16(af[i], bfr[j], acc[i][j], 0, 0, 0);
    }
    __syncthreads();
  }
}

// ---------------- GEMM1: qkv = xb @ Wt^T, scatter Q,K (bhsd) and V^T (bhds) ----------------
// grid (24, 32). All outputs routed through LDS transpose buffer for coalesced b128 stores.
__global__ __launch_bounds__(256) void k_gemm_qkv(const unsigned short* __restrict__ xb,
                                                  const unsigned short* __restrict__ Bw,
                                                  unsigned short* __restrict__ Qb,
                                                  unsigned short* __restrict__ Kb,
                                                  unsigned short* __restrict__ Vt) {
  __shared__ __align__(16) unsigned short smem[18432];
  f32x4 acc[4][4] = {};
  int bn = blockIdx.x, bm = blockIdx.y;
  gemm_core_async(xb, Bw, bm, bn, smem, acc);

  int t = threadIdx.x, lane = t & 63, w = t >> 6;
  int m16 = lane & 15, quad = lane >> 4;
  int wr = (w >> 1) * 64, wc = (w & 1) * 64;
  int b = bm >> 4, srow = (bm & 15) * 128;
  int which = bn >> 3;                  // 0=q 1=k 2=v (block-uniform)
  ushort_t (*Tr)[130] = (ushort_t(*)[130])smem;     // 33280 B <= 36864
  if (which < 2) {
    #pragma unroll
    for (int i = 0; i < 4; ++i)
      #pragma unroll
      for (int j = 0; j < 4; ++j)
        #pragma unroll
        for (int r = 0; r < 4; ++r)
          Tr[wr + i * 16 + quad * 4 + r][wc + j * 16 + m16] = bf16b(acc[i][j][r]);
    __syncthreads();
    int row = t >> 1, half = t & 1;
    int cloc = bn * 128 + half * 64 - which * 1024;
    int h = cloc >> 6;
    unsigned short* dst = (which ? Kb : Qb) +
        ((size_t)(b * 16 + h) * 2048 + srow + row) * 64;
    #pragma unroll
    for (int p = 0; p < 8; ++p)
      *(uint4*)(dst + p * 8) = *(const uint4*)(&Tr[row][half * 64 + p * 8]);
  } else {
    #pragma unroll
    for (int i = 0; i < 4; ++i)
      #pragma unroll
      for (int j = 0; j < 4; ++j)
        #pragma unroll
        for (int r = 0; r < 4; ++r)
          Tr[wc + j * 16 + m16][wr + i * 16 + quad * 4 + r] = bf16b(acc[i][j][r]);
    __syncthreads();
    int dl = t >> 1, half = t & 1;
    int cloc = (bn - 16) * 128 + dl;
    int h = cloc >> 6, d = cloc & 63;
    unsigned short* dst = Vt + ((size_t)(b * 16 + h) * 64 + d) * 2048 + srow + half * 64;
    #pragma unroll
    for (int p = 0; p < 8; ++p)
      *(uint4*)(dst + p * 8) = *(const uint4*)(&Tr[dl][half * 64 + p * 8]);
  }
}

// ---------------- flash attention: 8 waves x 32 q-rows, 3-deep LDS pipeline, counted vmcnt ----------------
// grid 256 x 512 threads: xcd = bid&7, jj = bid>>3, bh = (jj&3)*8+xcd, qtile = jj>>2 (8 tiles of 256 rows).
// Wave owns 32 q rows (two 16-row MFMA fragments) so each K/V LDS byte feeds 2 MFMAs — halves
// LDS read traffic per FLOP (the round-1 bottleneck: ~11 MB LDS traffic/CU ~= the 68 us floor).
// 1 block/CU (84 KB LDS); prefetch distance 2 (3 buffers), counted vmcnt, setprio on MFMA.
// LDS: Ks[3][64][64] | Vs[3][64][64] | P[8][32][68]  = 83968 B
__global__ __launch_bounds__(512, 2) void k_attn(const unsigned short* __restrict__ Qb,
                                                 const unsigned short* __restrict__ Kb,
                                                 const unsigned short* __restrict__ Vt,
                                                 unsigned short* __restrict__ AO) {
  __shared__ __align__(16) unsigned short smem[41984];   // 83968 B
  int t = threadIdx.x;
  int w = t >> 6, lane = t & 63;
  int m16 = lane & 15, quad = lane >> 4;
  int bid = blockIdx.x;
  int jj = bid >> 3;
  int bh = ((jj & 3) << 3) + (bid & 7);
  int qbase = (jj >> 2) * 256 + w * 32;

  const unsigned short* QpA = Qb + ((size_t)bh * S_LEN + qbase + m16) * DH + quad * 8;
  const unsigned short* QpB = QpA + 16 * DH;
  bf16x8 aq0A = *(const bf16x8*)(QpA);
  bf16x8 aq1A = *(const bf16x8*)(QpA + 32);
  bf16x8 aq0B = *(const bf16x8*)(QpB);
  bf16x8 aq1B = *(const bf16x8*)(QpB + 32);
  const unsigned short* Kbase = Kb + (size_t)bh * S_LEN * DH;
  const unsigned short* Vbase = Vt + (size_t)bh * DH * S_LEN;

  unsigned short* Pw = smem + 24576 + w * 2176;          // 32 x 68
  int xr = m16 & 7;

  // staging thread mapping: 512 threads, 1 K-chunk + 1 V-chunk each per tile
  int trow = t >> 3;            // 0..63
  int tcol = t & 7;
  int gswz = tcol ^ (trow & 7); // pre-swizzled global source; LDS dest stays linear
  const unsigned short* Kg = Kbase + (size_t)trow * 64 + gswz * 8;
  const unsigned short* Vg = Vbase + (size_t)trow * S_LEN + gswz * 8;
  unsigned short* Kl = smem + trow * 64 + tcol * 8;              // + slot*4096
  unsigned short* Vl = smem + 12288 + trow * 64 + tcol * 8;      // + slot*4096

  f32x4 oA[4] = {}, oB[4] = {};
  float lA = 0.f, lB = 0.f;
  f32x4 zero = {0.f, 0.f, 0.f, 0.f};

  // prologue: stage tiles 0,1 into slots 0,1 (4 loads/thread in flight)
  glds16(Kg,        Kl);
  glds16(Vg,        Vl);
  glds16(Kg + 4096, Kl + 4096);
  glds16(Vg + 64,   Vl + 4096);

  int buf = 0, slot = 2;
  #pragma unroll 1
  for (int kt = 0; kt < S_LEN / 64; ++kt) {
    // my tile-kt loads are the 2 oldest outstanding; allow tile kt+1's 2 to stay in flight
    if (kt + 1 < S_LEN / 64) asm volatile("s_waitcnt vmcnt(2)" ::: "memory");
    else                     asm volatile("s_waitcnt vmcnt(0)" ::: "memory");
    __builtin_amdgcn_s_barrier();            // everyone's tile-kt landed; everyone done reading kt-1
    __builtin_amdgcn_sched_barrier(0);       // keep ds_reads below the barrier
    if (kt + 2 < S_LEN / 64) {
      // writes the slot whose last readers finished before this barrier (WAR-safe)
      glds16(Kg + (size_t)(kt + 2) * 4096, Kl + slot * 4096);
      glds16(Vg + (kt + 2) * 64,           Vl + slot * 4096);
    }
    unsigned short* Ksh = smem + buf * 4096;
    unsigned short* Vsh = smem + 12288 + buf * 4096;

    // QK^T transposed: st[g] rows = keys g*16+quad*4+r, col = q-row m16.
    // Each K fragment read feeds BOTH q-fragments (the LDS-traffic halving).
    f32x4 stA[4], stB[4];
    __builtin_amdgcn_s_setprio(1);
    #pragma unroll
    for (int g = 0; g < 4; ++g) {
      int rk = g * 16 + m16;
      bf16x8 kf0 = *(const bf16x8*)(Ksh + rk * 64 + ((quad ^ xr) * 8));
      bf16x8 kf1 = *(const bf16x8*)(Ksh + rk * 64 + (((4 + quad) ^ xr) * 8));
      stA[g] = __builtin_amdgcn_mfma_f32_16x16x32_bf16(kf0, aq0A, zero, 0, 0, 0);
      stA[g] = __builtin_amdgcn_mfma_f32_16x16x32_bf16(kf1, aq1A, stA[g], 0, 0, 0);
      stB[g] = __builtin_amdgcn_mfma_f32_16x16x32_bf16(kf0, aq0B, zero, 0, 0, 0);
      stB[g] = __builtin_amdgcn_mfma_f32_16x16x32_bf16(kf1, aq1B, stB[g], 0, 0, 0);
    }
    __builtin_amdgcn_s_setprio(0);
    // softmax: p = 2^s (log2e folded into Wq), both fragments
    #pragma unroll
    for (int g = 0; g < 4; ++g) {
      float a0 = exp2v(stA[g][0]), a1 = exp2v(stA[g][1]);
      float a2 = exp2v(stA[g][2]), a3 = exp2v(stA[g][3]);
      lA += (a0 + a1) + (a2 + a3);
      uint2 pka;
      pka.x = ((unsigned)bf16b(a1) << 16) | bf16b(a0);
      pka.y = ((unsigned)bf16b(a3) << 16) | bf16b(a2);
      *(uint2*)(Pw + m16 * 68 + g * 16 + quad * 4) = pka;
      float b0 = exp2v(stB[g][0]), b1 = exp2v(stB[g][1]);
      float b2 = exp2v(stB[g][2]), b3 = exp2v(stB[g][3]);
      lB += (b0 + b1) + (b2 + b3);
      uint2 pkb;
      pkb.x = ((unsigned)bf16b(b1) << 16) | bf16b(b0);
      pkb.y = ((unsigned)bf16b(b3) << 16) | bf16b(b2);
      *(uint2*)(Pw + (16 + m16) * 68 + g * 16 + quad * 4) = pkb;
    }
    // PV: o(32q x 64d) += P(32x64) @ V^T(64keys x 64d); V read feeds both fragments
    __builtin_amdgcn_s_setprio(1);
    #pragma unroll
    for (int c = 0; c < 2; ++c) {
      bf16x8 apA = *(const bf16x8*)(Pw + m16 * 68 + c * 32 + quad * 8);
      bf16x8 apB = *(const bf16x8*)(Pw + (16 + m16) * 68 + c * 32 + quad * 8);
      #pragma unroll
      for (int j = 0; j < 4; ++j) {
        int dv = j * 16 + m16;
        bf16x8 bv = *(const bf16x8*)(Vsh + dv * 64 + (((c * 4 + quad) ^ xr) * 8));
        oA[j] = __builtin_amdgcn_mfma_f32_16x16x32_bf16(apA, bv, oA[j], 0, 0, 0);
        oB[j] = __builtin_amdgcn_mfma_f32_16x16x32_bf16(apB, bv, oB[j], 0, 0, 0);
      }
    }
    __builtin_amdgcn_s_setprio(0);
    buf  = (buf  == 2) ? 0 : buf  + 1;
    slot = (slot == 2) ? 0 : slot + 1;
  }

  lA += __shfl_xor(lA, 16); lA += __shfl_xor(lA, 32);
  lB += __shfl_xor(lB, 16); lB += __shfl_xor(lB, 32);
  float ivA = 1.0f / lA;
  float ivB = 1.0f / lB;
  int b = bh >> 4, h = bh & 15;
  #pragma unroll
  for (int r = 0; r < 4; ++r) {
    float vA = __shfl(ivA, quad * 4 + r);
    float vB = __shfl(ivB, quad * 4 + r);
    size_t row0 = (size_t)b * S_LEN + qbase + quad * 4 + r;
    unsigned short* d0 = AO + row0 * DM + h * DH + m16;
    unsigned short* d1 = AO + (row0 + 16) * DM + h * DH + m16;
    #pragma unroll
    for (int j = 0; j < 4; ++j) {
      d0[j * 16] = bf16b(oA[j][r] * vA);
      d1[j * 16] = bf16b(oB[j][r] * vB);
    }
  }
}

// ---------------- GEMM2: out = AO @ Wot^T + bias (fp32 out), grid (8, 32) ----------------
__global__ __launch_bounds__(256) void k_gemm_out(const unsigned short* __restrict__ A,
                                                  const unsigned short* __restrict__ Bw,
                                                  const float* __restrict__ bias,
                                                  float* __restrict__ out) {
  __shared__ __align__(16) unsigned short smem[18432];
  f32x4 acc[4][4] = {};
  int bn = blockIdx.x, bm = blockIdx.y;
  gemm_core_async(A, Bw, bm, bn, smem, acc);

  int t = threadIdx.x, lane = t & 63, w = t >> 6;
  int m16 = lane & 15, quad = lane >> 4;
  int wr = (w >> 1) * 64, wc = (w & 1) * 64;
  #pragma unroll
  for (int i = 0; i < 4; ++i) {
    int grow = bm * 128 + wr + i * 16 + quad * 4;
    #pragma unroll
    for (int j = 0; j < 4; ++j) {
      int gc = bn * 128 + wc + j * 16 + m16;
      float bb = bias[gc];
      #pragma unroll
      for (int r = 0; r < 4; ++r)
        out[(size_t)(grow + r) * DM + gc] = acc[i][j][r] + bb;
    }
  }
}

extern "C" void kernel_launch(void* const* d_in, const int* in_sizes, int n_in,
                              void* d_out, int out_size, void* d_ws, size_t ws_size,
                              hipStream_t stream) {
  const float* x    = (const float*)d_in[0];
  const float* wqkv = (const float*)d_in[1];
  const float* wout = (const float*)d_in[2];
  const float* bout = (const float*)d_in[3];
  const float* mlog = (const float*)d_in[4];
  char* ws = (char*)d_ws;
  unsigned short* Wt  = (unsigned short*)(ws + OFF_WT);
  unsigned short* Wot = (unsigned short*)(ws + OFF_WOT);
  unsigned short* Qb  = (unsigned short*)(ws + OFF_Q);
  unsigned short* Kb  = (unsigned short*)(ws + OFF_K);
  unsigned short* Vt  = (unsigned short*)(ws + OFF_V);
  unsigned short* xb  = (unsigned short*)(ws + OFF_AO);
  unsigned short* AO  = (unsigned short*)(ws + OFF_AO);
  float* out = (float*)d_out;

  k_prep<<<dim3(2816), dim3(256), 0, stream>>>(wqkv, wout, x, mlog, Wt, Wot, xb);
  k_gemm_qkv<<<dim3(24, 32), dim3(256), 0, stream>>>(xb, Wt, Qb, Kb, Vt);
  k_attn<<<dim3(256), dim3(512), 0, stream>>>(Qb, Kb, Vt, AO);
  k_gemm_out<<<dim3(8, 32), dim3(256), 0, stream>>>(AO, Wot, bout, out);
}

// Round 3
// 196.720 us; speedup vs baseline: 1.1125x; 1.1125x over previous
//
#include <hip/hip_runtime.h>

// Problem constants
#define S_LEN 2048
#define NH    16
#define DH    64
#define DM    1024
#define NQKV  3072

typedef __attribute__((ext_vector_type(8))) __bf16 bf16x8;
typedef __attribute__((ext_vector_type(4))) float  f32x4;
typedef unsigned short ushort_t;

static __device__ __forceinline__ unsigned short bf16b(float f) {
  return __builtin_bit_cast(unsigned short, (__bf16)f);
}

static __device__ __forceinline__ float exp2v(float x) {
  return __builtin_amdgcn_exp2f(x);   // v_exp_f32: D = 2^S0
}

static __device__ __forceinline__ bf16x8 pack8(float4 f0, float4 f1) {
  uint4 v;
  v.x = ((unsigned)bf16b(f0.y) << 16) | bf16b(f0.x);
  v.y = ((unsigned)bf16b(f0.w) << 16) | bf16b(f0.z);
  v.z = ((unsigned)bf16b(f1.y) << 16) | bf16b(f1.x);
  v.w = ((unsigned)bf16b(f1.w) << 16) | bf16b(f1.z);
  return __builtin_bit_cast(bf16x8, v);
}

static __device__ __forceinline__ void glds16(const void* g, void* l) {
  __builtin_amdgcn_global_load_lds((const __attribute__((address_space(1))) unsigned int*)g,
                                   (__attribute__((address_space(3))) unsigned int*)l, 16, 0, 0);
}

// ---------------- workspace layout (bytes) ----------------
#define OFF_WT  65536ull                          // 3072*1024*2
#define OFF_WOT 6356992ull                        // 1024*1024*2
#define OFF_Q   8454144ull                        // 8 MB
#define OFF_K   16842752ull                       // 8 MB
#define OFF_V   25231360ull                       // 8 MB
#define OFF_AO  33619968ull                       // 8 MB (xb before attn, AO after)

// ---------------- fused prep: fold (MFMA) | transpose | castx ----------------
// blocks 0..255: fold Wq/Wk via F @ W^T; 256..767: transpose v-part + wout; 768..2815: cast x.
__global__ __launch_bounds__(256) void k_prep(const float* __restrict__ wqkv,
                                              const float* __restrict__ wout,
                                              const float* __restrict__ x,
                                              const float* __restrict__ logits,
                                              unsigned short* __restrict__ Wt,
                                              unsigned short* __restrict__ Wot,
                                              unsigned short* __restrict__ xb) {
  __shared__ __align__(16) char sbuf[16640];
  int bid = blockIdx.x;
  int t = threadIdx.x;

  if (bid < 256) {
    // ---- fold: Wt[base+j][k] = sum_i F[j][i] * W[k][base+i], via MFMA ----
    float* msk = (float*)sbuf;                    // 33 f
    float* Kd  = (float*)(sbuf + 144);            // 64 f
    ushort_t (*Fb)[72] = (ushort_t(*)[72])(sbuf + 416);  // 64x72 bf16
    if (t < 33) msk[t] = 1.0f / (1.0f + __expf(-logits[t]));
    __syncthreads();
    if (t < 64) {
      float acc = msk[0];
      #pragma unroll
      for (int f = 1; f < 32; ++f) {
        int r = (f * t) & 63;
        acc += 2.0f * msk[f] * __cosf((float)r * (6.28318530717958647692f / 64.0f));
      }
      acc += msk[32] * ((t & 1) ? -1.0f : 1.0f);
      Kd[t] = acc * (1.0f / 64.0f);
    }
    __syncthreads();
    for (int idx = t; idx < 4096; idx += 256) {
      int j = idx >> 6, i = idx & 63;
      Fb[j][i] = bf16b(Kd[(j - i) & 63]);
    }
    __syncthreads();

    int lane = t & 63, w = t >> 6;
    int m16 = lane & 15, quad = lane >> 4;
    int kx = bid >> 5, yy = bid & 31;
    int which = yy >> 4, h = yy & 15;
    int base = which * 1024 + h * 64;

    bf16x8 af0 = *(const bf16x8*)(&Fb[w * 16 + m16][quad * 8]);
    bf16x8 af1 = *(const bf16x8*)(&Fb[w * 16 + m16][32 + quad * 8]);

    f32x4 acc[8] = {};
    #pragma unroll 2
    for (int n = 0; n < 8; ++n) {
      const float* Wg = wqkv + (size_t)(kx * 128 + n * 16 + m16) * NQKV + base + quad * 8;
      float4 a0 = *(const float4*)(Wg);
      float4 a1 = *(const float4*)(Wg + 4);
      float4 b0 = *(const float4*)(Wg + 32);
      float4 b1 = *(const float4*)(Wg + 36);
      acc[n] = __builtin_amdgcn_mfma_f32_16x16x32_bf16(af0, pack8(a0, a1), acc[n], 0, 0, 0);
      acc[n] = __builtin_amdgcn_mfma_f32_16x16x32_bf16(af1, pack8(b0, b1), acc[n], 0, 0, 0);
    }
    float sc = (which == 0) ? 0.18033688011112042f : 1.0f;   // 0.125 * log2(e) into q
    #pragma unroll
    for (int n = 0; n < 8; ++n) {
      #pragma unroll
      for (int r = 0; r < 4; ++r) {
        int j = w * 16 + quad * 4 + r;
        Wt[(size_t)(base + j) * DM + kx * 128 + n * 16 + m16] = bf16b(acc[n][r] * sc);
      }
    }
  } else if (bid < 768) {
    // ---- transpose+cast: v-part of w_qkv and w_out ----
    float (*Ts)[65] = (float(*)[65])sbuf;
    int b1 = bid - 256;
    if (b1 < 256) {
      int kt = b1 & 15, nt = b1 >> 4;
      int cb = 2048 + nt * 64, kbase = kt * 64;
      #pragma unroll
      for (int p = 0; p < 16; ++p) {
        int kk = p * 4 + (t >> 6);
        Ts[kk][t & 63] = wqkv[(size_t)(kbase + kk) * NQKV + cb + (t & 63)];
      }
      __syncthreads();
      #pragma unroll
      for (int p = 0; p < 16; ++p) {
        int nn = p * 4 + (t >> 6);
        Wt[(size_t)(cb + nn) * DM + kbase + (t & 63)] = bf16b(Ts[t & 63][nn]);
      }
    } else {
      int b2 = b1 - 256;
      int kt = b2 & 15, nt = b2 >> 4;
      int cb = nt * 64, kbase = kt * 64;
      #pragma unroll
      for (int p = 0; p < 16; ++p) {
        int kk = p * 4 + (t >> 6);
        Ts[kk][t & 63] = wout[(size_t)(kbase + kk) * DM + cb + (t & 63)];
      }
      __syncthreads();
      #pragma unroll
      for (int p = 0; p < 16; ++p) {
        int nn = p * 4 + (t >> 6);
        Wot[(size_t)(cb + nn) * DM + kbase + (t & 63)] = bf16b(Ts[t & 63][nn]);
      }
    }
  } else {
    // ---- x -> bf16 ----
    size_t i = ((size_t)(bid - 768) * 256 + t) * 8;
    const float4* xp = (const float4*)(x + i);
    float4 a = xp[0], b = xp[1];
    uint4 v;
    v.x = ((unsigned)bf16b(a.y) << 16) | bf16b(a.x);
    v.y = ((unsigned)bf16b(a.w) << 16) | bf16b(a.z);
    v.z = ((unsigned)bf16b(b.y) << 16) | bf16b(b.x);
    v.w = ((unsigned)bf16b(b.w) << 16) | bf16b(b.z);
    *(uint4*)(xb + i) = v;
  }
}

// ---------------- 128x128-tile GEMM core, m97-style: global_load_lds + XOR swizzle ----------------
__device__ __forceinline__ void gemm_core_async(const unsigned short* __restrict__ A,
                                                const unsigned short* __restrict__ Bw,
                                                int bm, int bn, unsigned short* smem,
                                                f32x4 (&acc)[4][4]) {
  unsigned short* As = smem;           // 8192 shorts
  unsigned short* Bs = smem + 8192;
  int t = threadIdx.x, lane = t & 63, w = t >> 6;
  int m16 = lane & 15, quad = lane >> 4;
  int wr = (w >> 1) * 64, wc = (w & 1) * 64;
  int lr = lane >> 3, lc = lane & 7;
  int gc = lc ^ lr;
  int xr = m16 & 7;
  const unsigned short* Agb = A  + (size_t)(bm * 128) * DM + gc * 8;
  const unsigned short* Bgb = Bw + (size_t)(bn * 128) * DM + gc * 8;

  for (int k0 = 0; k0 < DM; k0 += 64) {
    #pragma unroll
    for (int p = 0; p < 4; ++p) {
      int row = p * 32 + w * 8 + lr;
      glds16(Agb + (size_t)row * DM + k0, As + row * 64 + lc * 8);
      glds16(Bgb + (size_t)row * DM + k0, Bs + row * 64 + lc * 8);
    }
    __syncthreads();
    #pragma unroll
    for (int kk = 0; kk < 2; ++kk) {
      bf16x8 af[4], bfr[4];
      #pragma unroll
      for (int i = 0; i < 4; ++i)
        af[i] = *(const bf16x8*)(As + (wr + i * 16 + m16) * 64 + ((kk * 4 + quad) ^ xr) * 8);
      #pragma unroll
      for (int j = 0; j < 4; ++j)
        bfr[j] = *(const bf16x8*)(Bs + (wc + j * 16 + m16) * 64 + ((kk * 4 + quad) ^ xr) * 8);
      #pragma unroll
      for (int i = 0; i < 4; ++i)
        #pragma unroll
        for (int j = 0; j < 4; ++j)
          acc[i][j] = __builtin_amdgcn_mfma_f32_16x16x32_bf16(af[i], bfr[j], acc[i][j], 0, 0, 0);
    }
    __syncthreads();
  }
}

// ---------------- GEMM1: qkv = xb @ Wt^T, scatter Q,K (bhsd) and V^T (bhds) ----------------
// grid (24, 32). All outputs routed through LDS transpose buffer for coalesced b128 stores.
__global__ __launch_bounds__(256) void k_gemm_qkv(const unsigned short* __restrict__ xb,
                                                  const unsigned short* __restrict__ Bw,
                                                  unsigned short* __restrict__ Qb,
                                                  unsigned short* __restrict__ Kb,
                                                  unsigned short* __restrict__ Vt) {
  __shared__ __align__(16) unsigned short smem[18432];
  f32x4 acc[4][4] = {};
  int bn = blockIdx.x, bm = blockIdx.y;
  gemm_core_async(xb, Bw, bm, bn, smem, acc);

  int t = threadIdx.x, lane = t & 63, w = t >> 6;
  int m16 = lane & 15, quad = lane >> 4;
  int wr = (w >> 1) * 64, wc = (w & 1) * 64;
  int b = bm >> 4, srow = (bm & 15) * 128;
  int which = bn >> 3;                  // 0=q 1=k 2=v (block-uniform)
  ushort_t (*Tr)[130] = (ushort_t(*)[130])smem;     // 33280 B <= 36864
  if (which < 2) {
    #pragma unroll
    for (int i = 0; i < 4; ++i)
      #pragma unroll
      for (int j = 0; j < 4; ++j)
        #pragma unroll
        for (int r = 0; r < 4; ++r)
          Tr[wr + i * 16 + quad * 4 + r][wc + j * 16 + m16] = bf16b(acc[i][j][r]);
    __syncthreads();
    int row = t >> 1, half = t & 1;
    int cloc = bn * 128 + half * 64 - which * 1024;
    int h = cloc >> 6;
    unsigned short* dst = (which ? Kb : Qb) +
        ((size_t)(b * 16 + h) * 2048 + srow + row) * 64;
    #pragma unroll
    for (int p = 0; p < 8; ++p)
      *(uint4*)(dst + p * 8) = *(const uint4*)(&Tr[row][half * 64 + p * 8]);
  } else {
    #pragma unroll
    for (int i = 0; i < 4; ++i)
      #pragma unroll
      for (int j = 0; j < 4; ++j)
        #pragma unroll
        for (int r = 0; r < 4; ++r)
          Tr[wc + j * 16 + m16][wr + i * 16 + quad * 4 + r] = bf16b(acc[i][j][r]);
    __syncthreads();
    int dl = t >> 1, half = t & 1;
    int cloc = (bn - 16) * 128 + dl;
    int h = cloc >> 6, d = cloc & 63;
    unsigned short* dst = Vt + ((size_t)(b * 16 + h) * 64 + d) * 2048 + srow + half * 64;
    #pragma unroll
    for (int p = 0; p < 8; ++p)
      *(uint4*)(dst + p * 8) = *(const uint4*)(&Tr[dl][half * 64 + p * 8]);
  }
}

// ---------------- flash attention: 8 waves x 32 q-rows, 2-tile barrier windows ----------------
// grid 256 x 512 threads: xcd = bid&7, jj = bid>>3, bh = (jj&3)*8+xcd, qtile = jj>>2.
// THEORY (r2 post-mortem): one-barrier-per-tile locksteps all waves into the same
// QK -> softmax -> PV phase; pipes serialize (t_QK + t_SM + t_PV). Fix: process TWO
// k-tiles per barrier window so SM(a) overlaps QK(b) and SM(b) overlaps PV(a) across
// the VALU/MFMA/DS pipes. K/V: 4-slot ring staged pair-at-a-time (counted vmcnt(4));
// P: per-wave double buffer, stride-64 XOR-swizzled (b64 writes / b128 reads, conflict-free).
// LDS: K 4x8KB | V 4x8KB | P 8x2x[32][64] = 131072 B, 1 block/CU.
__global__ __launch_bounds__(512, 2) void k_attn(const unsigned short* __restrict__ Qb,
                                                 const unsigned short* __restrict__ Kb,
                                                 const unsigned short* __restrict__ Vt,
                                                 unsigned short* __restrict__ AO) {
  __shared__ __align__(16) unsigned short smem[65536];   // 131072 B
  int t = threadIdx.x;
  int w = t >> 6, lane = t & 63;
  int m16 = lane & 15, quad = lane >> 4;
  int bid = blockIdx.x;
  int jj = bid >> 3;
  int bh = ((jj & 3) << 3) + (bid & 7);
  int qbase = (jj >> 2) * 256 + w * 32;

  const unsigned short* QpA = Qb + ((size_t)bh * S_LEN + qbase + m16) * DH + quad * 8;
  const unsigned short* QpB = QpA + 16 * DH;
  bf16x8 aq0A = *(const bf16x8*)(QpA);
  bf16x8 aq1A = *(const bf16x8*)(QpA + 32);
  bf16x8 aq0B = *(const bf16x8*)(QpB);
  bf16x8 aq1B = *(const bf16x8*)(QpB + 32);
  const unsigned short* Kbase = Kb + (size_t)bh * S_LEN * DH;
  const unsigned short* Vbase = Vt + (size_t)bh * DH * S_LEN;

  int xr = m16 & 7;
  unsigned short* Pw = smem + 32768 + w * 4096;   // 2 tile-buffers x [32][64] shorts, swizzled

  // staging thread mapping: 512 threads, 1 K-chunk + 1 V-chunk each per tile
  int trow = t >> 3;            // 0..63
  int tcol = t & 7;
  int gswz = tcol ^ (trow & 7); // pre-swizzled global source; LDS dest stays linear
  const unsigned short* Kg = Kbase + (size_t)trow * 64 + gswz * 8;
  const unsigned short* Vg = Vbase + (size_t)trow * S_LEN + gswz * 8;
  unsigned short* Kl = smem + trow * 64 + tcol * 8;              // + slot*4096
  unsigned short* Vl = smem + 16384 + trow * 64 + tcol * 8;      // + slot*4096

  f32x4 oA[4] = {}, oB[4] = {};
  float lA = 0.f, lB = 0.f;
  f32x4 zero = {0.f, 0.f, 0.f, 0.f};

  // prologue: stage tiles 0..3 into slots 0..3 (8 loads/thread in flight)
  #pragma unroll
  for (int tt = 0; tt < 4; ++tt) {
    glds16(Kg + (size_t)tt * 4096, Kl + tt * 4096);
    glds16(Vg + tt * 64,           Vl + tt * 4096);
  }

  #pragma unroll 1
  for (int wnd = 0; wnd < 16; ++wnd) {
    // my window's pair (4 loads) are the oldest outstanding; next pair may stay in flight
    if (wnd < 15) asm volatile("s_waitcnt vmcnt(4)" ::: "memory");
    else          asm volatile("s_waitcnt vmcnt(0)" ::: "memory");
    __builtin_amdgcn_s_barrier();            // pair landed everywhere; prev window's reads done
    __builtin_amdgcn_sched_barrier(0);       // keep ds_reads below the barrier
    int sb = (wnd & 1) << 1;
    const unsigned short* Ka  = smem + sb * 4096;
    const unsigned short* Kbs = smem + (sb + 1) * 4096;
    const unsigned short* Va  = smem + 16384 + sb * 4096;
    const unsigned short* Vbs = smem + 16384 + (sb + 1) * 4096;
    unsigned short* Pa = Pw;
    unsigned short* Pb = Pw + 2048;

    // ---- QK tile a ----
    f32x4 saA[4], saB[4];
    #pragma unroll
    for (int g = 0; g < 4; ++g) {
      int rk = g * 16 + m16;
      bf16x8 kf0 = *(const bf16x8*)(Ka + rk * 64 + ((quad ^ xr) * 8));
      bf16x8 kf1 = *(const bf16x8*)(Ka + rk * 64 + (((4 + quad) ^ xr) * 8));
      saA[g] = __builtin_amdgcn_mfma_f32_16x16x32_bf16(kf0, aq0A, zero, 0, 0, 0);
      saA[g] = __builtin_amdgcn_mfma_f32_16x16x32_bf16(kf1, aq1A, saA[g], 0, 0, 0);
      saB[g] = __builtin_amdgcn_mfma_f32_16x16x32_bf16(kf0, aq0B, zero, 0, 0, 0);
      saB[g] = __builtin_amdgcn_mfma_f32_16x16x32_bf16(kf1, aq1B, saB[g], 0, 0, 0);
    }
    // ---- SM tile a -> Pa (overlaps QK tile b below across pipes) ----
    #pragma unroll
    for (int g = 0; g < 4; ++g) {
      int chw = (((2 * g + (quad >> 1)) ^ xr) << 3) + ((quad & 1) << 2);
      float a0 = exp2v(saA[g][0]), a1 = exp2v(saA[g][1]);
      float a2 = exp2v(saA[g][2]), a3 = exp2v(saA[g][3]);
      lA += (a0 + a1) + (a2 + a3);
      uint2 pka;
      pka.x = ((unsigned)bf16b(a1) << 16) | bf16b(a0);
      pka.y = ((unsigned)bf16b(a3) << 16) | bf16b(a2);
      *(uint2*)(Pa + m16 * 64 + chw) = pka;
      float b0 = exp2v(saB[g][0]), b1 = exp2v(saB[g][1]);
      float b2 = exp2v(saB[g][2]), b3 = exp2v(saB[g][3]);
      lB += (b0 + b1) + (b2 + b3);
      uint2 pkb;
      pkb.x = ((unsigned)bf16b(b1) << 16) | bf16b(b0);
      pkb.y = ((unsigned)bf16b(b3) << 16) | bf16b(b2);
      *(uint2*)(Pa + (16 + m16) * 64 + chw) = pkb;
    }
    // ---- QK tile b ----
    f32x4 sbA[4], sbB[4];
    #pragma unroll
    for (int g = 0; g < 4; ++g) {
      int rk = g * 16 + m16;
      bf16x8 kf0 = *(const bf16x8*)(Kbs + rk * 64 + ((quad ^ xr) * 8));
      bf16x8 kf1 = *(const bf16x8*)(Kbs + rk * 64 + (((4 + quad) ^ xr) * 8));
      sbA[g] = __builtin_amdgcn_mfma_f32_16x16x32_bf16(kf0, aq0A, zero, 0, 0, 0);
      sbA[g] = __builtin_amdgcn_mfma_f32_16x16x32_bf16(kf1, aq1A, sbA[g], 0, 0, 0);
      sbB[g] = __builtin_amdgcn_mfma_f32_16x16x32_bf16(kf0, aq0B, zero, 0, 0, 0);
      sbB[g] = __builtin_amdgcn_mfma_f32_16x16x32_bf16(kf1, aq1B, sbB[g], 0, 0, 0);
    }
    // ---- PV tile a ----
    #pragma unroll
    for (int c = 0; c < 2; ++c) {
      bf16x8 apA = *(const bf16x8*)(Pa + m16 * 64 + (((4 * c + quad) ^ xr) << 3));
      bf16x8 apB = *(const bf16x8*)(Pa + (16 + m16) * 64 + (((4 * c + quad) ^ xr) << 3));
      #pragma unroll
      for (int j = 0; j < 4; ++j) {
        int dv = j * 16 + m16;
        bf16x8 bv = *(const bf16x8*)(Va + dv * 64 + (((c * 4 + quad) ^ xr) * 8));
        oA[j] = __builtin_amdgcn_mfma_f32_16x16x32_bf16(apA, bv, oA[j], 0, 0, 0);
        oB[j] = __builtin_amdgcn_mfma_f32_16x16x32_bf16(apB, bv, oB[j], 0, 0, 0);
      }
    }
    // ---- SM tile b -> Pb ----
    #pragma unroll
    for (int g = 0; g < 4; ++g) {
      int chw = (((2 * g + (quad >> 1)) ^ xr) << 3) + ((quad & 1) << 2);
      float a0 = exp2v(sbA[g][0]), a1 = exp2v(sbA[g][1]);
      float a2 = exp2v(sbA[g][2]), a3 = exp2v(sbA[g][3]);
      lA += (a0 + a1) + (a2 + a3);
      uint2 pka;
      pka.x = ((unsigned)bf16b(a1) << 16) | bf16b(a0);
      pka.y = ((unsigned)bf16b(a3) << 16) | bf16b(a2);
      *(uint2*)(Pb + m16 * 64 + chw) = pka;
      float b0 = exp2v(sbB[g][0]), b1 = exp2v(sbB[g][1]);
      float b2 = exp2v(sbB[g][2]), b3 = exp2v(sbB[g][3]);
      lB += (b0 + b1) + (b2 + b3);
      uint2 pkb;
      pkb.x = ((unsigned)bf16b(b1) << 16) | bf16b(b0);
      pkb.y = ((unsigned)bf16b(b3) << 16) | bf16b(b2);
      *(uint2*)(Pb + (16 + m16) * 64 + chw) = pkb;
    }
    // ---- PV tile b ----
    #pragma unroll
    for (int c = 0; c < 2; ++c) {
      bf16x8 apA = *(const bf16x8*)(Pb + m16 * 64 + (((4 * c + quad) ^ xr) << 3));
      bf16x8 apB = *(const bf16x8*)(Pb + (16 + m16) * 64 + (((4 * c + quad) ^ xr) << 3));
      #pragma unroll
      for (int j = 0; j < 4; ++j) {
        int dv = j * 16 + m16;
        bf16x8 bv = *(const bf16x8*)(Vbs + dv * 64 + (((c * 4 + quad) ^ xr) * 8));
        oA[j] = __builtin_amdgcn_mfma_f32_16x16x32_bf16(apA, bv, oA[j], 0, 0, 0);
        oB[j] = __builtin_amdgcn_mfma_f32_16x16x32_bf16(apB, bv, oB[j], 0, 0, 0);
      }
    }
    // ---- refill just-freed pair of slots (WAR-safe: all reads of sb,sb+1 completed
    //      into VGPRs before each wave reaches this barrier) ----
    if (wnd < 14) {
      __builtin_amdgcn_s_barrier();
      int ta = 2 * wnd + 4;
      glds16(Kg + (size_t)ta * 4096,       Kl + sb * 4096);
      glds16(Vg + ta * 64,                 Vl + sb * 4096);
      glds16(Kg + (size_t)(ta + 1) * 4096, Kl + (sb + 1) * 4096);
      glds16(Vg + (ta + 1) * 64,           Vl + (sb + 1) * 4096);
    }
  }

  lA += __shfl_xor(lA, 16); lA += __shfl_xor(lA, 32);
  lB += __shfl_xor(lB, 16); lB += __shfl_xor(lB, 32);
  float ivA = 1.0f / lA;
  float ivB = 1.0f / lB;
  int b = bh >> 4, h = bh & 15;
  #pragma unroll
  for (int r = 0; r < 4; ++r) {
    float vA = __shfl(ivA, quad * 4 + r);
    float vB = __shfl(ivB, quad * 4 + r);
    size_t row0 = (size_t)b * S_LEN + qbase + quad * 4 + r;
    unsigned short* d0 = AO + row0 * DM + h * DH + m16;
    unsigned short* d1 = AO + (row0 + 16) * DM + h * DH + m16;
    #pragma unroll
    for (int j = 0; j < 4; ++j) {
      d0[j * 16] = bf16b(oA[j][r] * vA);
      d1[j * 16] = bf16b(oB[j][r] * vB);
    }
  }
}

// ---------------- GEMM2: out = AO @ Wot^T + bias (fp32 out), grid (8, 32) ----------------
__global__ __launch_bounds__(256) void k_gemm_out(const unsigned short* __restrict__ A,
                                                  const unsigned short* __restrict__ Bw,
                                                  const float* __restrict__ bias,
                                                  float* __restrict__ out) {
  __shared__ __align__(16) unsigned short smem[18432];
  f32x4 acc[4][4] = {};
  int bn = blockIdx.x, bm = blockIdx.y;
  gemm_core_async(A, Bw, bm, bn, smem, acc);

  int t = threadIdx.x, lane = t & 63, w = t >> 6;
  int m16 = lane & 15, quad = lane >> 4;
  int wr = (w >> 1) * 64, wc = (w & 1) * 64;
  #pragma unroll
  for (int i = 0; i < 4; ++i) {
    int grow = bm * 128 + wr + i * 16 + quad * 4;
    #pragma unroll
    for (int j = 0; j < 4; ++j) {
      int gc = bn * 128 + wc + j * 16 + m16;
      float bb = bias[gc];
      #pragma unroll
      for (int r = 0; r < 4; ++r)
        out[(size_t)(grow + r) * DM + gc] = acc[i][j][r] + bb;
    }
  }
}

extern "C" void kernel_launch(void* const* d_in, const int* in_sizes, int n_in,
                              void* d_out, int out_size, void* d_ws, size_t ws_size,
                              hipStream_t stream) {
  const float* x    = (const float*)d_in[0];
  const float* wqkv = (const float*)d_in[1];
  const float* wout = (const float*)d_in[2];
  const float* bout = (const float*)d_in[3];
  const float* mlog = (const float*)d_in[4];
  char* ws = (char*)d_ws;
  unsigned short* Wt  = (unsigned short*)(ws + OFF_WT);
  unsigned short* Wot = (unsigned short*)(ws + OFF_WOT);
  unsigned short* Qb  = (unsigned short*)(ws + OFF_Q);
  unsigned short* Kb  = (unsigned short*)(ws + OFF_K);
  unsigned short* Vt  = (unsigned short*)(ws + OFF_V);
  unsigned short* xb  = (unsigned short*)(ws + OFF_AO);
  unsigned short* AO  = (unsigned short*)(ws + OFF_AO);
  float* out = (float*)d_out;

  k_prep<<<dim3(2816), dim3(256), 0, stream>>>(wqkv, wout, x, mlog, Wt, Wot, xb);
  k_gemm_qkv<<<dim3(24, 32), dim3(256), 0, stream>>>(xb, Wt, Qb, Kb, Vt);
  k_attn<<<dim3(256), dim3(512), 0, stream>>>(Qb, Kb, Vt, AO);
  k_gemm_out<<<dim3(8, 32), dim3(256), 0, stream>>>(AO, Wot, bout, out);
}

// Round 4
// 186.969 us; speedup vs baseline: 1.1705x; 1.0522x over previous
//
#include <hip/hip_runtime.h>

// Problem constants
#define S_LEN 2048
#define NH    16
#define DH    64
#define DM    1024
#define NQKV  3072

typedef __attribute__((ext_vector_type(8))) __bf16 bf16x8;
typedef __attribute__((ext_vector_type(4))) float  f32x4;
typedef unsigned short ushort_t;

static __device__ __forceinline__ unsigned short bf16b(float f) {
  return __builtin_bit_cast(unsigned short, (__bf16)f);
}

static __device__ __forceinline__ float exp2v(float x) {
  return __builtin_amdgcn_exp2f(x);   // v_exp_f32: D = 2^S0
}

static __device__ __forceinline__ bf16x8 pack8(float4 f0, float4 f1) {
  uint4 v;
  v.x = ((unsigned)bf16b(f0.y) << 16) | bf16b(f0.x);
  v.y = ((unsigned)bf16b(f0.w) << 16) | bf16b(f0.z);
  v.z = ((unsigned)bf16b(f1.y) << 16) | bf16b(f1.x);
  v.w = ((unsigned)bf16b(f1.w) << 16) | bf16b(f1.z);
  return __builtin_bit_cast(bf16x8, v);
}

static __device__ __forceinline__ void glds16(const void* g, void* l) {
  __builtin_amdgcn_global_load_lds((const __attribute__((address_space(1))) unsigned int*)g,
                                   (__attribute__((address_space(3))) unsigned int*)l, 16, 0, 0);
}

// ---------------- workspace layout (bytes) ----------------
#define OFF_WT  65536ull                          // 3072*1024*2
#define OFF_WOT 6356992ull                        // 1024*1024*2
#define OFF_Q   8454144ull                        // 8 MB
#define OFF_K   16842752ull                       // 8 MB
#define OFF_V   25231360ull                       // 8 MB
#define OFF_AO  33619968ull                       // 8 MB (xb before attn, AO after)

// ---------------- fused prep: fold (MFMA) | transpose | castx ----------------
// blocks 0..255: fold Wq/Wk via F @ W^T; 256..767: transpose v-part + wout; 768..2815: cast x.
__global__ __launch_bounds__(256) void k_prep(const float* __restrict__ wqkv,
                                              const float* __restrict__ wout,
                                              const float* __restrict__ x,
                                              const float* __restrict__ logits,
                                              unsigned short* __restrict__ Wt,
                                              unsigned short* __restrict__ Wot,
                                              unsigned short* __restrict__ xb) {
  __shared__ __align__(16) char sbuf[16640];
  int bid = blockIdx.x;
  int t = threadIdx.x;

  if (bid < 256) {
    // ---- fold: Wt[base+j][k] = sum_i F[j][i] * W[k][base+i], via MFMA ----
    float* msk = (float*)sbuf;                    // 33 f
    float* Kd  = (float*)(sbuf + 144);            // 64 f
    ushort_t (*Fb)[72] = (ushort_t(*)[72])(sbuf + 416);  // 64x72 bf16
    if (t < 33) msk[t] = 1.0f / (1.0f + __expf(-logits[t]));
    __syncthreads();
    if (t < 64) {
      float acc = msk[0];
      #pragma unroll
      for (int f = 1; f < 32; ++f) {
        int r = (f * t) & 63;
        acc += 2.0f * msk[f] * __cosf((float)r * (6.28318530717958647692f / 64.0f));
      }
      acc += msk[32] * ((t & 1) ? -1.0f : 1.0f);
      Kd[t] = acc * (1.0f / 64.0f);
    }
    __syncthreads();
    for (int idx = t; idx < 4096; idx += 256) {
      int j = idx >> 6, i = idx & 63;
      Fb[j][i] = bf16b(Kd[(j - i) & 63]);
    }
    __syncthreads();

    int lane = t & 63, w = t >> 6;
    int m16 = lane & 15, quad = lane >> 4;
    int kx = bid >> 5, yy = bid & 31;
    int which = yy >> 4, h = yy & 15;
    int base = which * 1024 + h * 64;

    bf16x8 af0 = *(const bf16x8*)(&Fb[w * 16 + m16][quad * 8]);
    bf16x8 af1 = *(const bf16x8*)(&Fb[w * 16 + m16][32 + quad * 8]);

    f32x4 acc[8] = {};
    #pragma unroll 2
    for (int n = 0; n < 8; ++n) {
      const float* Wg = wqkv + (size_t)(kx * 128 + n * 16 + m16) * NQKV + base + quad * 8;
      float4 a0 = *(const float4*)(Wg);
      float4 a1 = *(const float4*)(Wg + 4);
      float4 b0 = *(const float4*)(Wg + 32);
      float4 b1 = *(const float4*)(Wg + 36);
      acc[n] = __builtin_amdgcn_mfma_f32_16x16x32_bf16(af0, pack8(a0, a1), acc[n], 0, 0, 0);
      acc[n] = __builtin_amdgcn_mfma_f32_16x16x32_bf16(af1, pack8(b0, b1), acc[n], 0, 0, 0);
    }
    float sc = (which == 0) ? 0.18033688011112042f : 1.0f;   // 0.125 * log2(e) into q
    #pragma unroll
    for (int n = 0; n < 8; ++n) {
      #pragma unroll
      for (int r = 0; r < 4; ++r) {
        int j = w * 16 + quad * 4 + r;
        Wt[(size_t)(base + j) * DM + kx * 128 + n * 16 + m16] = bf16b(acc[n][r] * sc);
      }
    }
  } else if (bid < 768) {
    // ---- transpose+cast: v-part of w_qkv and w_out ----
    float (*Ts)[65] = (float(*)[65])sbuf;
    int b1 = bid - 256;
    if (b1 < 256) {
      int kt = b1 & 15, nt = b1 >> 4;
      int cb = 2048 + nt * 64, kbase = kt * 64;
      #pragma unroll
      for (int p = 0; p < 16; ++p) {
        int kk = p * 4 + (t >> 6);
        Ts[kk][t & 63] = wqkv[(size_t)(kbase + kk) * NQKV + cb + (t & 63)];
      }
      __syncthreads();
      #pragma unroll
      for (int p = 0; p < 16; ++p) {
        int nn = p * 4 + (t >> 6);
        Wt[(size_t)(cb + nn) * DM + kbase + (t & 63)] = bf16b(Ts[t & 63][nn]);
      }
    } else {
      int b2 = b1 - 256;
      int kt = b2 & 15, nt = b2 >> 4;
      int cb = nt * 64, kbase = kt * 64;
      #pragma unroll
      for (int p = 0; p < 16; ++p) {
        int kk = p * 4 + (t >> 6);
        Ts[kk][t & 63] = wout[(size_t)(kbase + kk) * DM + cb + (t & 63)];
      }
      __syncthreads();
      #pragma unroll
      for (int p = 0; p < 16; ++p) {
        int nn = p * 4 + (t >> 6);
        Wot[(size_t)(cb + nn) * DM + kbase + (t & 63)] = bf16b(Ts[t & 63][nn]);
      }
    }
  } else {
    // ---- x -> bf16 ----
    size_t i = ((size_t)(bid - 768) * 256 + t) * 8;
    const float4* xp = (const float4*)(x + i);
    float4 a = xp[0], b = xp[1];
    uint4 v;
    v.x = ((unsigned)bf16b(a.y) << 16) | bf16b(a.x);
    v.y = ((unsigned)bf16b(a.w) << 16) | bf16b(a.z);
    v.z = ((unsigned)bf16b(b.y) << 16) | bf16b(b.x);
    v.w = ((unsigned)bf16b(b.w) << 16) | bf16b(b.z);
    *(uint4*)(xb + i) = v;
  }
}

// ---------------- 128x128-tile GEMM core: 4-slot LDS ring, 2-K-step windows, counted vmcnt ----
// r3 theory: the old stage -> syncthreads(vmcnt0) -> compute structure serializes full memory
// latency every K-step (nothing co-resident to overlap with at ~1 block/CU). Same fix that won
// in k_attn: ring of 4 {A,B} slots (32 KB each, 128 KB), window = 2 K-steps, vmcnt(16) at window
// top (my pair is oldest; next pair stays in flight), stage the next pair after a second barrier
// (WAR-safe; loads get a full compute window to land). 8 windows for K=1024.
__device__ __forceinline__ void gemm_core_async(const unsigned short* __restrict__ A,
                                                const unsigned short* __restrict__ Bw,
                                                int bm, int bn, unsigned short* smem,
                                                f32x4 (&acc)[4][4]) {
  int t = threadIdx.x, lane = t & 63, w = t >> 6;
  int m16 = lane & 15, quad = lane >> 4;
  int wr = (w >> 1) * 64, wc = (w & 1) * 64;
  int lr = lane >> 3, lc = lane & 7;
  int gc = lc ^ lr;
  int xr = m16 & 7;
  const unsigned short* Agb = A  + (size_t)(bm * 128) * DM + gc * 8;
  const unsigned short* Bgb = Bw + (size_t)(bn * 128) * DM + gc * 8;
  int srow = w * 8 + lr;                 // this thread's staging rows: srow + p*32
  unsigned short* Al = smem + srow * 64 + lc * 8;          // + slot*16384
  unsigned short* Bl = smem + 8192 + srow * 64 + lc * 8;   // + slot*16384

  // prologue: stage K-steps 0..3 into slots 0..3 (32 loads/thread in flight)
  #pragma unroll
  for (int s = 0; s < 4; ++s) {
    #pragma unroll
    for (int p = 0; p < 4; ++p) {
      int row = p * 32 + srow;
      glds16(Agb + (size_t)row * DM + s * 64, Al + s * 16384 + p * 2048);
      glds16(Bgb + (size_t)row * DM + s * 64, Bl + s * 16384 + p * 2048);
    }
  }

  #pragma unroll 1
  for (int wnd = 0; wnd < 8; ++wnd) {
    if (wnd < 7) asm volatile("s_waitcnt vmcnt(16)" ::: "memory");
    else         asm volatile("s_waitcnt vmcnt(0)" ::: "memory");
    __builtin_amdgcn_s_barrier();          // my window's pair landed everywhere; prev reads done
    __builtin_amdgcn_sched_barrier(0);     // keep ds_reads below the barrier
    int sb = (wnd & 1) << 1;
    #pragma unroll
    for (int half = 0; half < 2; ++half) {
      const unsigned short* As = smem + (sb + half) * 16384;
      const unsigned short* Bs = As + 8192;
      #pragma unroll
      for (int kk = 0; kk < 2; ++kk) {
        bf16x8 af[4], bfr[4];
        #pragma unroll
        for (int i = 0; i < 4; ++i)
          af[i] = *(const bf16x8*)(As + (wr + i * 16 + m16) * 64 + ((kk * 4 + quad) ^ xr) * 8);
        #pragma unroll
        for (int j = 0; j < 4; ++j)
          bfr[j] = *(const bf16x8*)(Bs + (wc + j * 16 + m16) * 64 + ((kk * 4 + quad) ^ xr) * 8);
        #pragma unroll
        for (int i = 0; i < 4; ++i)
          #pragma unroll
          for (int j = 0; j < 4; ++j)
            acc[i][j] = __builtin_amdgcn_mfma_f32_16x16x32_bf16(af[i], bfr[j], acc[i][j], 0, 0, 0);
      }
    }
    // refill the just-freed pair of slots (all waves' reads completed before this barrier)
    if (wnd < 6) {
      __builtin_amdgcn_s_barrier();
      int ka = 2 * wnd + 4;                // K-steps ka, ka+1 -> slots sb, sb+1
      #pragma unroll
      for (int half = 0; half < 2; ++half) {
        #pragma unroll
        for (int p = 0; p < 4; ++p) {
          int row = p * 32 + srow;
          glds16(Agb + (size_t)row * DM + (ka + half) * 64, Al + (sb + half) * 16384 + p * 2048);
          glds16(Bgb + (size_t)row * DM + (ka + half) * 64, Bl + (sb + half) * 16384 + p * 2048);
        }
      }
    }
  }
  __syncthreads();   // epilogue reuses smem (Tr buffer)
}

// ---------------- GEMM1: qkv = xb @ Wt^T, scatter Q,K (bhsd) and V^T (bhds) ----------------
// grid (24, 32). All outputs routed through LDS transpose buffer for coalesced b128 stores.
__global__ __launch_bounds__(256) void k_gemm_qkv(const unsigned short* __restrict__ xb,
                                                  const unsigned short* __restrict__ Bw,
                                                  unsigned short* __restrict__ Qb,
                                                  unsigned short* __restrict__ Kb,
                                                  unsigned short* __restrict__ Vt) {
  __shared__ __align__(16) unsigned short smem[65536];   // 131072 B (ring; Tr reuses)
  f32x4 acc[4][4] = {};
  int bn = blockIdx.x, bm = blockIdx.y;
  gemm_core_async(xb, Bw, bm, bn, smem, acc);

  int t = threadIdx.x, lane = t & 63, w = t >> 6;
  int m16 = lane & 15, quad = lane >> 4;
  int wr = (w >> 1) * 64, wc = (w & 1) * 64;
  int b = bm >> 4, srow = (bm & 15) * 128;
  int which = bn >> 3;                  // 0=q 1=k 2=v (block-uniform)
  ushort_t (*Tr)[130] = (ushort_t(*)[130])smem;     // 33280 B <= 131072
  if (which < 2) {
    #pragma unroll
    for (int i = 0; i < 4; ++i)
      #pragma unroll
      for (int j = 0; j < 4; ++j)
        #pragma unroll
        for (int r = 0; r < 4; ++r)
          Tr[wr + i * 16 + quad * 4 + r][wc + j * 16 + m16] = bf16b(acc[i][j][r]);
    __syncthreads();
    int row = t >> 1, half = t & 1;
    int cloc = bn * 128 + half * 64 - which * 1024;
    int h = cloc >> 6;
    unsigned short* dst = (which ? Kb : Qb) +
        ((size_t)(b * 16 + h) * 2048 + srow + row) * 64;
    #pragma unroll
    for (int p = 0; p < 8; ++p)
      *(uint4*)(dst + p * 8) = *(const uint4*)(&Tr[row][half * 64 + p * 8]);
  } else {
    #pragma unroll
    for (int i = 0; i < 4; ++i)
      #pragma unroll
      for (int j = 0; j < 4; ++j)
        #pragma unroll
        for (int r = 0; r < 4; ++r)
          Tr[wc + j * 16 + m16][wr + i * 16 + quad * 4 + r] = bf16b(acc[i][j][r]);
    __syncthreads();
    int dl = t >> 1, half = t & 1;
    int cloc = (bn - 16) * 128 + dl;
    int h = cloc >> 6, d = cloc & 63;
    unsigned short* dst = Vt + ((size_t)(b * 16 + h) * 64 + d) * 2048 + srow + half * 64;
    #pragma unroll
    for (int p = 0; p < 8; ++p)
      *(uint4*)(dst + p * 8) = *(const uint4*)(&Tr[dl][half * 64 + p * 8]);
  }
}

// ---------------- flash attention: 8 waves x 32 q-rows, 2-tile barrier windows ----------------
// grid 256 x 512 threads: xcd = bid&7, jj = bid>>3, bh = (jj&3)*8+xcd, qtile = jj>>2.
// Two k-tiles per barrier window so SM(a) overlaps QK(b) and SM(b) overlaps PV(a) across
// the VALU/MFMA/DS pipes. K/V: 4-slot ring staged pair-at-a-time (counted vmcnt(4));
// P: per-wave double buffer, stride-64 XOR-swizzled. LDS 131072 B, 1 block/CU.
__global__ __launch_bounds__(512, 2) void k_attn(const unsigned short* __restrict__ Qb,
                                                 const unsigned short* __restrict__ Kb,
                                                 const unsigned short* __restrict__ Vt,
                                                 unsigned short* __restrict__ AO) {
  __shared__ __align__(16) unsigned short smem[65536];   // 131072 B
  int t = threadIdx.x;
  int w = t >> 6, lane = t & 63;
  int m16 = lane & 15, quad = lane >> 4;
  int bid = blockIdx.x;
  int jj = bid >> 3;
  int bh = ((jj & 3) << 3) + (bid & 7);
  int qbase = (jj >> 2) * 256 + w * 32;

  const unsigned short* QpA = Qb + ((size_t)bh * S_LEN + qbase + m16) * DH + quad * 8;
  const unsigned short* QpB = QpA + 16 * DH;
  bf16x8 aq0A = *(const bf16x8*)(QpA);
  bf16x8 aq1A = *(const bf16x8*)(QpA + 32);
  bf16x8 aq0B = *(const bf16x8*)(QpB);
  bf16x8 aq1B = *(const bf16x8*)(QpB + 32);
  const unsigned short* Kbase = Kb + (size_t)bh * S_LEN * DH;
  const unsigned short* Vbase = Vt + (size_t)bh * DH * S_LEN;

  int xr = m16 & 7;
  unsigned short* Pw = smem + 32768 + w * 4096;   // 2 tile-buffers x [32][64] shorts, swizzled

  // staging thread mapping: 512 threads, 1 K-chunk + 1 V-chunk each per tile
  int trow = t >> 3;            // 0..63
  int tcol = t & 7;
  int gswz = tcol ^ (trow & 7); // pre-swizzled global source; LDS dest stays linear
  const unsigned short* Kg = Kbase + (size_t)trow * 64 + gswz * 8;
  const unsigned short* Vg = Vbase + (size_t)trow * S_LEN + gswz * 8;
  unsigned short* Kl = smem + trow * 64 + tcol * 8;              // + slot*4096
  unsigned short* Vl = smem + 16384 + trow * 64 + tcol * 8;      // + slot*4096

  f32x4 oA[4] = {}, oB[4] = {};
  float lA = 0.f, lB = 0.f;
  f32x4 zero = {0.f, 0.f, 0.f, 0.f};

  // prologue: stage tiles 0..3 into slots 0..3 (8 loads/thread in flight)
  #pragma unroll
  for (int tt = 0; tt < 4; ++tt) {
    glds16(Kg + (size_t)tt * 4096, Kl + tt * 4096);
    glds16(Vg + tt * 64,           Vl + tt * 4096);
  }

  #pragma unroll 1
  for (int wnd = 0; wnd < 16; ++wnd) {
    // my window's pair (4 loads) are the oldest outstanding; next pair may stay in flight
    if (wnd < 15) asm volatile("s_waitcnt vmcnt(4)" ::: "memory");
    else          asm volatile("s_waitcnt vmcnt(0)" ::: "memory");
    __builtin_amdgcn_s_barrier();            // pair landed everywhere; prev window's reads done
    __builtin_amdgcn_sched_barrier(0);       // keep ds_reads below the barrier
    int sb = (wnd & 1) << 1;
    const unsigned short* Ka  = smem + sb * 4096;
    const unsigned short* Kbs = smem + (sb + 1) * 4096;
    const unsigned short* Va  = smem + 16384 + sb * 4096;
    const unsigned short* Vbs = smem + 16384 + (sb + 1) * 4096;
    unsigned short* Pa = Pw;
    unsigned short* Pb = Pw + 2048;

    // ---- QK tile a ----
    f32x4 saA[4], saB[4];
    #pragma unroll
    for (int g = 0; g < 4; ++g) {
      int rk = g * 16 + m16;
      bf16x8 kf0 = *(const bf16x8*)(Ka + rk * 64 + ((quad ^ xr) * 8));
      bf16x8 kf1 = *(const bf16x8*)(Ka + rk * 64 + (((4 + quad) ^ xr) * 8));
      saA[g] = __builtin_amdgcn_mfma_f32_16x16x32_bf16(kf0, aq0A, zero, 0, 0, 0);
      saA[g] = __builtin_amdgcn_mfma_f32_16x16x32_bf16(kf1, aq1A, saA[g], 0, 0, 0);
      saB[g] = __builtin_amdgcn_mfma_f32_16x16x32_bf16(kf0, aq0B, zero, 0, 0, 0);
      saB[g] = __builtin_amdgcn_mfma_f32_16x16x32_bf16(kf1, aq1B, saB[g], 0, 0, 0);
    }
    // ---- SM tile a -> Pa (overlaps QK tile b below across pipes) ----
    #pragma unroll
    for (int g = 0; g < 4; ++g) {
      int chw = (((2 * g + (quad >> 1)) ^ xr) << 3) + ((quad & 1) << 2);
      float a0 = exp2v(saA[g][0]), a1 = exp2v(saA[g][1]);
      float a2 = exp2v(saA[g][2]), a3 = exp2v(saA[g][3]);
      lA += (a0 + a1) + (a2 + a3);
      uint2 pka;
      pka.x = ((unsigned)bf16b(a1) << 16) | bf16b(a0);
      pka.y = ((unsigned)bf16b(a3) << 16) | bf16b(a2);
      *(uint2*)(Pa + m16 * 64 + chw) = pka;
      float b0 = exp2v(saB[g][0]), b1 = exp2v(saB[g][1]);
      float b2 = exp2v(saB[g][2]), b3 = exp2v(saB[g][3]);
      lB += (b0 + b1) + (b2 + b3);
      uint2 pkb;
      pkb.x = ((unsigned)bf16b(b1) << 16) | bf16b(b0);
      pkb.y = ((unsigned)bf16b(b3) << 16) | bf16b(b2);
      *(uint2*)(Pa + (16 + m16) * 64 + chw) = pkb;
    }
    // ---- QK tile b ----
    f32x4 sbA[4], sbB[4];
    #pragma unroll
    for (int g = 0; g < 4; ++g) {
      int rk = g * 16 + m16;
      bf16x8 kf0 = *(const bf16x8*)(Kbs + rk * 64 + ((quad ^ xr) * 8));
      bf16x8 kf1 = *(const bf16x8*)(Kbs + rk * 64 + (((4 + quad) ^ xr) * 8));
      sbA[g] = __builtin_amdgcn_mfma_f32_16x16x32_bf16(kf0, aq0A, zero, 0, 0, 0);
      sbA[g] = __builtin_amdgcn_mfma_f32_16x16x32_bf16(kf1, aq1A, sbA[g], 0, 0, 0);
      sbB[g] = __builtin_amdgcn_mfma_f32_16x16x32_bf16(kf0, aq0B, zero, 0, 0, 0);
      sbB[g] = __builtin_amdgcn_mfma_f32_16x16x32_bf16(kf1, aq1B, sbB[g], 0, 0, 0);
    }
    // ---- PV tile a ----
    #pragma unroll
    for (int c = 0; c < 2; ++c) {
      bf16x8 apA = *(const bf16x8*)(Pa + m16 * 64 + (((4 * c + quad) ^ xr) << 3));
      bf16x8 apB = *(const bf16x8*)(Pa + (16 + m16) * 64 + (((4 * c + quad) ^ xr) << 3));
      #pragma unroll
      for (int j = 0; j < 4; ++j) {
        int dv = j * 16 + m16;
        bf16x8 bv = *(const bf16x8*)(Va + dv * 64 + (((c * 4 + quad) ^ xr) * 8));
        oA[j] = __builtin_amdgcn_mfma_f32_16x16x32_bf16(apA, bv, oA[j], 0, 0, 0);
        oB[j] = __builtin_amdgcn_mfma_f32_16x16x32_bf16(apB, bv, oB[j], 0, 0, 0);
      }
    }
    // ---- SM tile b -> Pb ----
    #pragma unroll
    for (int g = 0; g < 4; ++g) {
      int chw = (((2 * g + (quad >> 1)) ^ xr) << 3) + ((quad & 1) << 2);
      float a0 = exp2v(sbA[g][0]), a1 = exp2v(sbA[g][1]);
      float a2 = exp2v(sbA[g][2]), a3 = exp2v(sbA[g][3]);
      lA += (a0 + a1) + (a2 + a3);
      uint2 pka;
      pka.x = ((unsigned)bf16b(a1) << 16) | bf16b(a0);
      pka.y = ((unsigned)bf16b(a3) << 16) | bf16b(a2);
      *(uint2*)(Pb + m16 * 64 + chw) = pka;
      float b0 = exp2v(sbB[g][0]), b1 = exp2v(sbB[g][1]);
      float b2 = exp2v(sbB[g][2]), b3 = exp2v(sbB[g][3]);
      lB += (b0 + b1) + (b2 + b3);
      uint2 pkb;
      pkb.x = ((unsigned)bf16b(b1) << 16) | bf16b(b0);
      pkb.y = ((unsigned)bf16b(b3) << 16) | bf16b(b2);
      *(uint2*)(Pb + (16 + m16) * 64 + chw) = pkb;
    }
    // ---- PV tile b ----
    #pragma unroll
    for (int c = 0; c < 2; ++c) {
      bf16x8 apA = *(const bf16x8*)(Pb + m16 * 64 + (((4 * c + quad) ^ xr) << 3));
      bf16x8 apB = *(const bf16x8*)(Pb + (16 + m16) * 64 + (((4 * c + quad) ^ xr) << 3));
      #pragma unroll
      for (int j = 0; j < 4; ++j) {
        int dv = j * 16 + m16;
        bf16x8 bv = *(const bf16x8*)(Vbs + dv * 64 + (((c * 4 + quad) ^ xr) * 8));
        oA[j] = __builtin_amdgcn_mfma_f32_16x16x32_bf16(apA, bv, oA[j], 0, 0, 0);
        oB[j] = __builtin_amdgcn_mfma_f32_16x16x32_bf16(apB, bv, oB[j], 0, 0, 0);
      }
    }
    // ---- refill just-freed pair of slots (WAR-safe: all reads of sb,sb+1 completed
    //      into VGPRs before each wave reaches this barrier) ----
    if (wnd < 14) {
      __builtin_amdgcn_s_barrier();
      int ta = 2 * wnd + 4;
      glds16(Kg + (size_t)ta * 4096,       Kl + sb * 4096);
      glds16(Vg + ta * 64,                 Vl + sb * 4096);
      glds16(Kg + (size_t)(ta + 1) * 4096, Kl + (sb + 1) * 4096);
      glds16(Vg + (ta + 1) * 64,           Vl + (sb + 1) * 4096);
    }
  }

  lA += __shfl_xor(lA, 16); lA += __shfl_xor(lA, 32);
  lB += __shfl_xor(lB, 16); lB += __shfl_xor(lB, 32);
  float ivA = 1.0f / lA;
  float ivB = 1.0f / lB;
  int b = bh >> 4, h = bh & 15;
  #pragma unroll
  for (int r = 0; r < 4; ++r) {
    float vA = __shfl(ivA, quad * 4 + r);
    float vB = __shfl(ivB, quad * 4 + r);
    size_t row0 = (size_t)b * S_LEN + qbase + quad * 4 + r;
    unsigned short* d0 = AO + row0 * DM + h * DH + m16;
    unsigned short* d1 = AO + (row0 + 16) * DM + h * DH + m16;
    #pragma unroll
    for (int j = 0; j < 4; ++j) {
      d0[j * 16] = bf16b(oA[j][r] * vA);
      d1[j * 16] = bf16b(oB[j][r] * vB);
    }
  }
}

// ---------------- GEMM2: out = AO @ Wot^T + bias (fp32 out), grid (8, 32) ----------------
__global__ __launch_bounds__(256) void k_gemm_out(const unsigned short* __restrict__ A,
                                                  const unsigned short* __restrict__ Bw,
                                                  const float* __restrict__ bias,
                                                  float* __restrict__ out) {
  __shared__ __align__(16) unsigned short smem[65536];   // 131072 B (ring)
  f32x4 acc[4][4] = {};
  int bn = blockIdx.x, bm = blockIdx.y;
  gemm_core_async(A, Bw, bm, bn, smem, acc);

  int t = threadIdx.x, lane = t & 63, w = t >> 6;
  int m16 = lane & 15, quad = lane >> 4;
  int wr = (w >> 1) * 64, wc = (w & 1) * 64;
  #pragma unroll
  for (int i = 0; i < 4; ++i) {
    int grow = bm * 128 + wr + i * 16 + quad * 4;
    #pragma unroll
    for (int j = 0; j < 4; ++j) {
      int gc = bn * 128 + wc + j * 16 + m16;
      float bb = bias[gc];
      #pragma unroll
      for (int r = 0; r < 4; ++r)
        out[(size_t)(grow + r) * DM + gc] = acc[i][j][r] + bb;
    }
  }
}

extern "C" void kernel_launch(void* const* d_in, const int* in_sizes, int n_in,
                              void* d_out, int out_size, void* d_ws, size_t ws_size,
                              hipStream_t stream) {
  const float* x    = (const float*)d_in[0];
  const float* wqkv = (const float*)d_in[1];
  const float* wout = (const float*)d_in[2];
  const float* bout = (const float*)d_in[3];
  const float* mlog = (const float*)d_in[4];
  char* ws = (char*)d_ws;
  unsigned short* Wt  = (unsigned short*)(ws + OFF_WT);
  unsigned short* Wot = (unsigned short*)(ws + OFF_WOT);
  unsigned short* Qb  = (unsigned short*)(ws + OFF_Q);
  unsigned short* Kb  = (unsigned short*)(ws + OFF_K);
  unsigned short* Vt  = (unsigned short*)(ws + OFF_V);
  unsigned short* xb  = (unsigned short*)(ws + OFF_AO);
  unsigned short* AO  = (unsigned short*)(ws + OFF_AO);
  float* out = (float*)d_out;

  k_prep<<<dim3(2816), dim3(256), 0, stream>>>(wqkv, wout, x, mlog, Wt, Wot, xb);
  k_gemm_qkv<<<dim3(24, 32), dim3(256), 0, stream>>>(xb, Wt, Qb, Kb, Vt);
  k_attn<<<dim3(256), dim3(512), 0, stream>>>(Qb, Kb, Vt, AO);
  k_gemm_out<<<dim3(8, 32), dim3(256), 0, stream>>>(AO, Wot, bout, out);
}